// Round 5
// baseline (2614.877 us; speedup 1.0000x reference)
//
#include <hip/hip_runtime.h>
#include <hip/hip_bf16.h>
#include <cstdint>
#include <cstddef>

#define N_NODES 20000
#define N_EDGES 640000
#define HID     128
#define OUT_DIM 64
#define NSTEPS  16
#define HSTEP   0.1f

typedef unsigned short u16;
typedef __attribute__((ext_vector_type(8))) short short8;   // 8 bf16 (4 VGPRs)
typedef __attribute__((ext_vector_type(4))) float f32x4;    // MFMA C/D

__device__ __forceinline__ float bf2f(u16 u) {
    union { unsigned int i; float f; } v; v.i = ((unsigned int)u) << 16; return v.f;
}
__device__ __forceinline__ u16 f2bf(float f) {
    union { float f; unsigned int i; } v; v.f = f;
    unsigned int x = v.i;
    unsigned int r = x + 0x7FFFu + ((x >> 16) & 1u);   // round-to-nearest-even
    return (u16)(r >> 16);
}

__device__ __forceinline__ float sigm(float x) { return 1.f / (1.f + __expf(-x)); }
__device__ __forceinline__ float tanh_fast(float x) {
    float e2 = __expf(-2.f * fabsf(x));
    float t = (1.f - e2) / (1.f + e2);
    return copysignf(t, x);
}

// ---------------------------------------------------------------------------
// Storage-dtype detection. flag=1 -> tensors stored as f32; flag=0 -> bf16.
// ---------------------------------------------------------------------------
__global__ void detect_kernel(const u16* __restrict__ xraw, int* __restrict__ flag) {
    __shared__ int cnt;
    if (threadIdx.x == 0) cnt = 0;
    __syncthreads();
    int c = 0;
    for (int i = threadIdx.x; i < 4096; i += 256) {
        int e = (xraw[i] >> 7) & 0xFF;
        if (e >= 0x90) c++;
    }
    atomicAdd(&cnt, c);
    __syncthreads();
    if (threadIdx.x == 0) *flag = (cnt > 100) ? 1 : 0;
}

// ---------------------------------------------------------------------------
// Packed conversion of the 15 weight/bias tensors into contiguous f32 ws.
// ---------------------------------------------------------------------------
#define N_CVT 15
struct CvtArgs { const void* s[N_CVT]; };
__constant__ const int cvt_off[N_CVT + 1] = {
    0, 16384, 16512, 32896, 33024, 98560, 164096, 164608, 165120,
    230656, 231168, 231680, 264448, 264576, 272768, 272832 };

__global__ void convert_kernel(CvtArgs a, float* __restrict__ dst,
                               const int* __restrict__ flag) {
    int i = blockIdx.x * blockDim.x + threadIdx.x;
    if (i >= 272832) return;
    int seg = 0;
    #pragma unroll
    for (int s = 1; s < N_CVT; ++s) if (i >= cvt_off[s]) seg = s;
    int j = i - cvt_off[seg];
    float v = (*flag) ? ((const float*)a.s[seg])[j]
                      : bf2f(((const u16*)a.s[seg])[j]);
    dst[i] = v;
}

// Build bf16 weights for MFMA: Wcat[512][256] = [Wihf | Whhf], Wb[512][128] = Wihb
__global__ void build_wbf_kernel(const float* __restrict__ wsf,
                                 u16* __restrict__ Wcat, u16* __restrict__ Wb) {
    int i = blockIdx.x * blockDim.x + threadIdx.x;
    if (i < 512 * 256) {
        int n = i >> 8, k = i & 255;
        const float* Wihf = wsf + 33024;
        const float* Whhf = wsf + 98560;
        float v = (k < 128) ? Wihf[n * 128 + k] : Whhf[n * 128 + (k - 128)];
        Wcat[i] = f2bf(v);
    }
    if (i < 512 * 128) {
        const float* Wihb = wsf + 165120;
        Wb[i] = f2bf(Wihb[i]);
    }
}

// ---------------------------------------------------------------------------
// CSR build: degree count -> exclusive scan -> bucket fill
// ---------------------------------------------------------------------------
__global__ void count_kernel(const int* __restrict__ ei, int* __restrict__ deg) {
    int e = blockIdx.x * blockDim.x + threadIdx.x;
    if (e < N_EDGES) atomicAdd(&deg[ei[N_EDGES + e]], 1);
}

__global__ __launch_bounds__(1024) void scan_kernel(const int* __restrict__ deg,
                                                    int* __restrict__ rowptr,
                                                    float* __restrict__ degf) {
    __shared__ int sd[1024];
    const int t = threadIdx.x;
    const int CH = (N_NODES + 1023) / 1024;   // 20
    int base = t * CH;
    int s = 0;
    for (int i = 0; i < CH; ++i) {
        int idx = base + i;
        if (idx < N_NODES) s += deg[idx];
    }
    sd[t] = s;
    __syncthreads();
    for (int off = 1; off < 1024; off <<= 1) {
        int v = (t >= off) ? sd[t - off] : 0;
        __syncthreads();
        sd[t] += v;
        __syncthreads();
    }
    int run = (t == 0) ? 0 : sd[t - 1];
    for (int i = 0; i < CH; ++i) {
        int idx = base + i;
        if (idx < N_NODES) {
            rowptr[idx] = run;
            degf[idx] = (float)deg[idx];
            run += deg[idx];
        }
    }
    if (t == 1023) rowptr[N_NODES] = sd[1023];
}

__global__ void fill_kernel(const int* __restrict__ ei, const int* __restrict__ rowptr,
                            int* __restrict__ fill, int* __restrict__ csr) {
    int e = blockIdx.x * blockDim.x + threadIdx.x;
    if (e < N_EDGES) {
        int d = ei[N_EDGES + e];
        int p = atomicAdd(&fill[d], 1);
        csr[rowptr[d] + p] = ei[e];
    }
}

// ---------------------------------------------------------------------------
// Tiled VALU GEMM (encoder + head): C[M,N] = A[M,K] @ W[N,K]^T + bias.
// DUAL_A: A=[A0|A1] split at K0. A_BF16_ALL: A halves stored bf16.
// aflag (runtime): non-dual A dtype follows detected storage (x input).
// OUT_FLAG: store f32/bf16 per *oflag. BF_COPY: also write bf16 copy to Cbf.
// ---------------------------------------------------------------------------
template<bool DUAL_A, bool A_BF16_ALL, bool RELU, bool OUT_FLAG, bool BF_COPY>
__global__ __launch_bounds__(256) void gemm_kernel(
    const void* __restrict__ A0v, const void* __restrict__ A1v,
    const float* __restrict__ W0, const float* __restrict__ bias0,
    void* __restrict__ Cv, u16* __restrict__ Cbf, int M, int N, int K, int K0,
    const int* __restrict__ aflag, const int* __restrict__ oflag)
{
    __shared__ float As[16][68];
    __shared__ float Ws[16][68];
    const int tid = threadIdx.x;
    const int m0 = blockIdx.x * 64;
    const int n0 = blockIdx.y * 64;
    const int ty = tid >> 4, tx = tid & 15;
    const int lm = tid >> 2;          // 0..63
    const int k4 = (tid & 3) * 4;     // 0,4,8,12

    const bool a_bf16_rt = (aflag != nullptr) && (*aflag == 0);

    float acc[4][4] = {};

    for (int kc = 0; kc < K; kc += 16) {
        // --- A tile: As[k][m] ---
        {
            int gm = m0 + lm;
            float av0 = 0.f, av1 = 0.f, av2 = 0.f, av3 = 0.f;
            if (gm < M) {
                int kg = kc + k4;
                const void* Av = (DUAL_A && kg >= K0) ? A1v : A0v;
                int kl = (DUAL_A && kg >= K0) ? (kg - K0) : kg;
                int lda = DUAL_A ? ((kg >= K0) ? (K - K0) : K0) : K;
                if (A_BF16_ALL || (!DUAL_A && a_bf16_rt)) {
                    ushort4 u = *(const ushort4*)((const u16*)Av + (size_t)gm * lda + kl);
                    av0 = bf2f(u.x); av1 = bf2f(u.y); av2 = bf2f(u.z); av3 = bf2f(u.w);
                } else {
                    float4 f = *(const float4*)((const float*)Av + (size_t)gm * lda + kl);
                    av0 = f.x; av1 = f.y; av2 = f.z; av3 = f.w;
                }
            }
            As[k4 + 0][lm] = av0; As[k4 + 1][lm] = av1;
            As[k4 + 2][lm] = av2; As[k4 + 3][lm] = av3;
        }
        // --- W tile: Ws[k][n] ---
        {
            int gn = n0 + lm;            // N multiple of 64 -> no guard
            int kg = kc + k4;
            float4 f = *(const float4*)(W0 + (size_t)gn * K + kg);
            Ws[k4 + 0][lm] = f.x; Ws[k4 + 1][lm] = f.y;
            Ws[k4 + 2][lm] = f.z; Ws[k4 + 3][lm] = f.w;
        }
        __syncthreads();
        #pragma unroll
        for (int k = 0; k < 16; ++k) {
            float4 a = *(const float4*)&As[k][ty * 4];
            float4 b = *(const float4*)&Ws[k][tx * 4];
            float aa[4] = {a.x, a.y, a.z, a.w};
            float bb[4] = {b.x, b.y, b.z, b.w};
            #pragma unroll
            for (int i = 0; i < 4; ++i)
                #pragma unroll
                for (int j = 0; j < 4; ++j)
                    acc[i][j] += aa[i] * bb[j];
        }
        __syncthreads();
    }

    float bv[4];
    #pragma unroll
    for (int j = 0; j < 4; ++j) bv[j] = bias0[n0 + tx * 4 + j];

    const bool out_bf16 = OUT_FLAG && (*oflag == 0);

    #pragma unroll
    for (int i = 0; i < 4; ++i) {
        int gm = m0 + ty * 4 + i;
        if (gm >= M) continue;
        float o0 = acc[i][0] + bv[0], o1 = acc[i][1] + bv[1];
        float o2 = acc[i][2] + bv[2], o3 = acc[i][3] + bv[3];
        if (RELU) {
            o0 = fmaxf(o0, 0.f); o1 = fmaxf(o1, 0.f);
            o2 = fmaxf(o2, 0.f); o3 = fmaxf(o3, 0.f);
        }
        size_t co = (size_t)gm * N + n0 + tx * 4;
        if (out_bf16) {
            ushort4 u; u.x = f2bf(o0); u.y = f2bf(o1); u.z = f2bf(o2); u.w = f2bf(o3);
            *(ushort4*)((u16*)Cv + co) = u;
        } else {
            *(float4*)((float*)Cv + co) = make_float4(o0, o1, o2, o3);
        }
        if (BF_COPY) {
            ushort4 u; u.x = f2bf(o0); u.y = f2bf(o1); u.z = f2bf(o2); u.w = f2bf(o3);
            *(ushort4*)(Cbf + co) = u;
        }
    }
}

// ---------------------------------------------------------------------------
// MFMA fused LSTM step. Block = 32 rows (2 m-tiles), 4 waves.
// Wave w owns within-quadrant col slice q*128 + w*32 + [0,32) for q=0..3
// -> matched (i,f,g,o) accumulators per lane -> cell epilogue in registers.
// ---------------------------------------------------------------------------
template<bool HAS_H>
__global__ __launch_bounds__(256) void lstm_mfma_kernel(
    const u16* __restrict__ Xbf,     // [N_NODES][128] bf16
    const u16* __restrict__ hbf_in,  // prev h bf16 (HAS_H only)
    u16* __restrict__ hbf_out,       // h out bf16
    float* __restrict__ cf,          // c in/out f32 (HAS_H only)
    const u16* __restrict__ Wcat,    // [512][KK] bf16
    const float* __restrict__ bih, const float* __restrict__ bhh)
{
    constexpr int KK = HAS_H ? 256 : 128;
    const int w = threadIdx.x >> 6;
    const int l = threadIdx.x & 63;
    const int l15 = l & 15, quad = l >> 4;
    const int m0 = blockIdx.x * 32;
    const int kof = quad * 8;

    f32x4 acc[2][4][2] = {};   // [m-tile][gate-quadrant][n-subtile]

    const size_t rowA0 = (size_t)(m0 + l15) * HID + kof;
    const size_t rowA1 = (size_t)(m0 + 16 + l15) * HID + kof;

    #pragma unroll
    for (int kc = 0; kc < KK; kc += 32) {
        const u16* Ab = (HAS_H && kc >= 128) ? hbf_in : Xbf;
        int kl = (HAS_H && kc >= 128) ? (kc - 128) : kc;
        short8 a0 = *(const short8*)(Ab + rowA0 + kl);
        short8 a1 = *(const short8*)(Ab + rowA1 + kl);
        #pragma unroll
        for (int q = 0; q < 4; ++q) {
            #pragma unroll
            for (int t = 0; t < 2; ++t) {
                int n = q * 128 + w * 32 + t * 16 + l15;
                short8 b = *(const short8*)(Wcat + (size_t)n * KK + kc + kof);
                acc[0][q][t] = __builtin_amdgcn_mfma_f32_16x16x32_bf16(a0, b, acc[0][q][t], 0, 0, 0);
                acc[1][q][t] = __builtin_amdgcn_mfma_f32_16x16x32_bf16(a1, b, acc[1][q][t], 0, 0, 0);
            }
        }
    }

    // cell epilogue: C/D layout col = l&15, row = quad*4 + reg
    #pragma unroll
    for (int t = 0; t < 2; ++t) {
        int j = w * 32 + t * 16 + l15;
        float bI = bih[j]       + bhh[j];
        float bF = bih[128 + j] + bhh[128 + j];
        float bG = bih[256 + j] + bhh[256 + j];
        float bO = bih[384 + j] + bhh[384 + j];
        #pragma unroll
        for (int mt = 0; mt < 2; ++mt) {
            #pragma unroll
            for (int i = 0; i < 4; ++i) {
                int m = m0 + mt * 16 + quad * 4 + i;
                size_t off = (size_t)m * HID + j;
                float gi = sigm(acc[mt][0][t][i] + bI);
                float gf = sigm(acc[mt][1][t][i] + bF);
                float gg = tanh_fast(acc[mt][2][t][i] + bG);
                float go = sigm(acc[mt][3][t][i] + bO);
                float cn;
                if (HAS_H) {
                    cn = gf * cf[off] + gi * gg;
                    cf[off] = cn;
                } else {
                    cn = gi * gg;
                }
                hbf_out[off] = f2bf(go * tanh_fast(cn));
            }
        }
    }
}

// ---------------------------------------------------------------------------
// Wave step, feature-sliced for L2-resident gathers.
// 8 slices of 16 feats: one slice of X = 20000*16*4B = 1.28 MB < 4 MB/XCD L2.
// Grid slice-major (bid = s*1250 + nb) so co-resident blocks share a slice.
// Block = 16 nodes x 16 feats. Each edge-gather touches one aligned 64B line.
// ---------------------------------------------------------------------------
__global__ __launch_bounds__(256) void wave_kernel(
    const float* __restrict__ Xc, float* __restrict__ Xn, u16* __restrict__ Xnbf,
    float* __restrict__ Y, const float* __restrict__ degf,
    const int* __restrict__ rowptr, const int* __restrict__ csr)
{
    const int s  = blockIdx.x / 1250;          // feature slice 0..7
    const int nb = blockIdx.x % 1250;
    const int nl = threadIdx.x >> 4;           // node-local 0..15
    const int f  = (threadIdx.x & 15) + s * 16;
    const int node = nb * 16 + nl;

    const int beg = rowptr[node], end = rowptr[node + 1];
    float a = 0.f;
    for (int i = beg; i < end; ++i) {
        int v = csr[i];
        a += Xc[(size_t)v * HID + f];
    }
    const size_t off = (size_t)node * HID + f;
    float xv = Xc[off];
    float d  = degf[node];
    float y  = Y[off] - HSTEP * (d * xv - a);
    Y[off] = y;
    float xn = xv + HSTEP * y;
    Xn[off] = xn;
    Xnbf[off] = f2bf(xn);
}

// ---------------------------------------------------------------------------
extern "C" void kernel_launch(void* const* d_in, const int* in_sizes, int n_in,
                              void* d_out, int out_size, void* d_ws, size_t ws_size,
                              hipStream_t stream)
{
    const void* x  = d_in[0];
    const int*  ei = (const int*)d_in[1];

    const size_t SZ_NH  = (size_t)N_NODES * HID * sizeof(float);   // 10,240,000
    const size_t SZ_NHB = (size_t)N_NODES * HID * sizeof(u16);     //  5,120,000
    const size_t SZ_I   = 80128;

    char* p = (char*)d_ws;
    float* Xa   = (float*)p; p += SZ_NH;
    float* Xb   = (float*)p; p += SZ_NH;
    float* Y    = (float*)p; p += SZ_NH;
    float* cf   = (float*)p; p += SZ_NH;
    u16*   hbf  = (u16*)p;   p += SZ_NHB;
    u16*   Xbf  = (u16*)p;   p += SZ_NHB;
    int*   deg  = (int*)p;   p += SZ_I;
    int*   fill = (int*)p;   p += SZ_I;
    int*   rowp = (int*)p;   p += SZ_I;
    float* degf = (float*)p; p += SZ_I;
    int*   csr  = (int*)p;   p += (size_t)N_EDGES * sizeof(int);
    int*   flag = (int*)p;   p += 128;
    float* wsf  = (float*)p; p += 272832 * sizeof(float);
    u16*   Wcat = (u16*)p;   p += 512 * 256 * sizeof(u16);
    u16*   Wb   = (u16*)p;   p += 512 * 128 * sizeof(u16);

    // converted f32 weight sub-pointers (offsets match cvt_off)
    float* Wenc1 = wsf + 0;
    float* benc1 = wsf + 16384;
    float* Wenc2 = wsf + 16512;
    float* benc2 = wsf + 32896;
    float* bihf  = wsf + 164096;
    float* bhhf  = wsf + 164608;
    float* bihb  = wsf + 230656;
    float* bhhb  = wsf + 231168;
    float* Wf1   = wsf + 231680;
    float* bf1   = wsf + 264448;
    float* Wf2   = wsf + 264576;
    float* bf2_  = wsf + 272768;

    float* H1   = Xb;        // encoder intermediate; Xb dead until wave t=1
    u16*   hbbf = (u16*)Y;   // backward h bf16; Y dead after last wave step

    hipMemsetAsync(Y, 0, 2 * SZ_NH + SZ_NHB, stream);   // Y, cf, hbf (contiguous)
    hipMemsetAsync(deg, 0, 2 * SZ_I, stream);           // deg, fill (contiguous)

    // dtype detect + weight conversion (f32 master, bf16 MFMA copies)
    detect_kernel<<<1, 256, 0, stream>>>((const u16*)x, flag);
    CvtArgs ca;
    ca.s[0] = d_in[2];  ca.s[1] = d_in[3];  ca.s[2] = d_in[4];  ca.s[3] = d_in[5];
    ca.s[4] = d_in[6];  ca.s[5] = d_in[7];  ca.s[6] = d_in[8];  ca.s[7] = d_in[9];
    ca.s[8] = d_in[10]; ca.s[9] = d_in[12]; ca.s[10] = d_in[13];
    ca.s[11] = d_in[14]; ca.s[12] = d_in[15]; ca.s[13] = d_in[16]; ca.s[14] = d_in[17];
    convert_kernel<<<(272832 + 255) / 256, 256, 0, stream>>>(ca, wsf, flag);
    build_wbf_kernel<<<512, 256, 0, stream>>>(wsf, Wcat, Wb);

    // CSR build
    count_kernel<<<(N_EDGES + 255) / 256, 256, 0, stream>>>(ei, deg);
    scan_kernel<<<1, 1024, 0, stream>>>(deg, rowp, degf);
    fill_kernel<<<(N_EDGES + 255) / 256, 256, 0, stream>>>(ei, rowp, fill, csr);

    const int MB = (N_NODES + 63) / 64;   // 313

    // encoder: H1 = relu(x @ Wenc1^T + b1); Xa = H1 @ Wenc2^T + b2 (+ bf16 copy)
    gemm_kernel<false, false, true, false, false><<<dim3(MB, 2), 256, 0, stream>>>(
        x, nullptr, Wenc1, benc1, H1, nullptr, N_NODES, HID, HID, HID, flag, nullptr);
    gemm_kernel<false, false, false, false, true><<<dim3(MB, 2), 256, 0, stream>>>(
        H1, nullptr, Wenc2, benc2, Xa, Xbf, N_NODES, HID, HID, HID, nullptr, nullptr);

    // wave scan interleaved with forward LSTM (MFMA fused gate-GEMM + cell)
    float* Xbuf[2] = {Xa, Xb};
    int cur = 0;
    for (int t = 0; t < NSTEPS; ++t) {
        if (t > 0) {
            wave_kernel<<<8 * 1250, 256, 0, stream>>>(
                Xbuf[cur], Xbuf[1 - cur], Xbf, Y, degf, rowp, csr);
            cur ^= 1;
        }
        lstm_mfma_kernel<true><<<N_NODES / 32, 256, 0, stream>>>(
            Xbf, hbf, hbf, cf, Wcat, bihf, bhhf);
    }

    // backward LSTM: only hs_b[0] used -> one cell on X_tilde[15], zero state
    lstm_mfma_kernel<false><<<N_NODES / 32, 256, 0, stream>>>(
        Xbf, nullptr, hbbf, nullptr, Wb, bihb, bhhb);

    // head: F1 = relu([hbf | hbbf] @ Wf1^T + bf1); out = F1 @ Wf2^T + bf2
    float* F1 = Xbuf[1 - cur];   // dead X buffer
    gemm_kernel<true, true, true, false, false><<<dim3(MB, 2), 256, 0, stream>>>(
        hbf, hbbf, Wf1, bf1, F1, nullptr, N_NODES, HID, 2 * HID, HID, nullptr, nullptr);
    gemm_kernel<false, false, false, true, false><<<dim3(MB, 1), 256, 0, stream>>>(
        F1, nullptr, Wf2, bf2_, d_out, nullptr, N_NODES, OUT_DIM, HID, HID, nullptr, flag);
}

// Round 6
// 1524.798 us; speedup vs baseline: 1.7149x; 1.7149x over previous
//
#include <hip/hip_runtime.h>
#include <hip/hip_bf16.h>
#include <cstdint>
#include <cstddef>

#define N_NODES 20000
#define N_EDGES 640000
#define HID     128
#define OUT_DIM 64
#define NSTEPS  16
#define HSTEP   0.1f

typedef unsigned short u16;
typedef __attribute__((ext_vector_type(8))) short short8;   // 8 bf16 (4 VGPRs)
typedef __attribute__((ext_vector_type(4))) float f32x4;    // MFMA C/D

__device__ __forceinline__ float bf2f(u16 u) {
    union { unsigned int i; float f; } v; v.i = ((unsigned int)u) << 16; return v.f;
}
__device__ __forceinline__ u16 f2bf(float f) {
    union { float f; unsigned int i; } v; v.f = f;
    unsigned int x = v.i;
    unsigned int r = x + 0x7FFFu + ((x >> 16) & 1u);   // round-to-nearest-even
    return (u16)(r >> 16);
}

__device__ __forceinline__ float sigm(float x) { return 1.f / (1.f + __expf(-x)); }
__device__ __forceinline__ float tanh_fast(float x) {
    float e2 = __expf(-2.f * fabsf(x));
    float t = (1.f - e2) / (1.f + e2);
    return copysignf(t, x);
}

// ---------------------------------------------------------------------------
// Storage-dtype detection. flag=1 -> tensors stored as f32; flag=0 -> bf16.
// ---------------------------------------------------------------------------
__global__ void detect_kernel(const u16* __restrict__ xraw, int* __restrict__ flag) {
    __shared__ int cnt;
    if (threadIdx.x == 0) cnt = 0;
    __syncthreads();
    int c = 0;
    for (int i = threadIdx.x; i < 4096; i += 256) {
        int e = (xraw[i] >> 7) & 0xFF;
        if (e >= 0x90) c++;
    }
    atomicAdd(&cnt, c);
    __syncthreads();
    if (threadIdx.x == 0) *flag = (cnt > 100) ? 1 : 0;
}

// ---------------------------------------------------------------------------
// Packed conversion of the 15 weight/bias tensors into contiguous f32 ws.
// ---------------------------------------------------------------------------
#define N_CVT 15
struct CvtArgs { const void* s[N_CVT]; };
__constant__ const int cvt_off[N_CVT + 1] = {
    0, 16384, 16512, 32896, 33024, 98560, 164096, 164608, 165120,
    230656, 231168, 231680, 264448, 264576, 272768, 272832 };

__global__ void convert_kernel(CvtArgs a, float* __restrict__ dst,
                               const int* __restrict__ flag) {
    int i = blockIdx.x * blockDim.x + threadIdx.x;
    if (i >= 272832) return;
    int seg = 0;
    #pragma unroll
    for (int s = 1; s < N_CVT; ++s) if (i >= cvt_off[s]) seg = s;
    int j = i - cvt_off[seg];
    float v = (*flag) ? ((const float*)a.s[seg])[j]
                      : bf2f(((const u16*)a.s[seg])[j]);
    dst[i] = v;
}

// Build bf16 weights for MFMA: Wcat[512][256] = [Wihf | Whhf], Wb[512][128] = Wihb
__global__ void build_wbf_kernel(const float* __restrict__ wsf,
                                 u16* __restrict__ Wcat, u16* __restrict__ Wb) {
    int i = blockIdx.x * blockDim.x + threadIdx.x;
    if (i < 512 * 256) {
        int n = i >> 8, k = i & 255;
        const float* Wihf = wsf + 33024;
        const float* Whhf = wsf + 98560;
        float v = (k < 128) ? Wihf[n * 128 + k] : Whhf[n * 128 + (k - 128)];
        Wcat[i] = f2bf(v);
    }
    if (i < 512 * 128) {
        const float* Wihb = wsf + 165120;
        Wb[i] = f2bf(Wihb[i]);
    }
}

// ---------------------------------------------------------------------------
// CSR build: degree count -> exclusive scan -> bucket fill
// ---------------------------------------------------------------------------
__global__ void count_kernel(const int* __restrict__ ei, int* __restrict__ deg) {
    int e = blockIdx.x * blockDim.x + threadIdx.x;
    if (e < N_EDGES) atomicAdd(&deg[ei[N_EDGES + e]], 1);
}

__global__ __launch_bounds__(1024) void scan_kernel(const int* __restrict__ deg,
                                                    int* __restrict__ rowptr,
                                                    float* __restrict__ degf) {
    __shared__ int sd[1024];
    const int t = threadIdx.x;
    const int CH = (N_NODES + 1023) / 1024;   // 20
    int base = t * CH;
    int s = 0;
    for (int i = 0; i < CH; ++i) {
        int idx = base + i;
        if (idx < N_NODES) s += deg[idx];
    }
    sd[t] = s;
    __syncthreads();
    for (int off = 1; off < 1024; off <<= 1) {
        int v = (t >= off) ? sd[t - off] : 0;
        __syncthreads();
        sd[t] += v;
        __syncthreads();
    }
    int run = (t == 0) ? 0 : sd[t - 1];
    for (int i = 0; i < CH; ++i) {
        int idx = base + i;
        if (idx < N_NODES) {
            rowptr[idx] = run;
            degf[idx] = (float)deg[idx];
            run += deg[idx];
        }
    }
    if (t == 1023) rowptr[N_NODES] = sd[1023];
}

__global__ void fill_kernel(const int* __restrict__ ei, const int* __restrict__ rowptr,
                            int* __restrict__ fill, int* __restrict__ csr) {
    int e = blockIdx.x * blockDim.x + threadIdx.x;
    if (e < N_EDGES) {
        int d = ei[N_EDGES + e];
        int p = atomicAdd(&fill[d], 1);
        csr[rowptr[d] + p] = ei[e];
    }
}

// ---------------------------------------------------------------------------
// Tiled VALU GEMM (encoder + head): C[M,N] = A[M,K] @ W[N,K]^T + bias.
// DUAL_A: A=[A0|A1] split at K0. A_BF16_ALL: A halves stored bf16.
// aflag (runtime): non-dual A dtype follows detected storage (x input).
// OUT_FLAG: store f32/bf16 per *oflag. BF_COPY: also write bf16 copy to Cbf.
// ---------------------------------------------------------------------------
template<bool DUAL_A, bool A_BF16_ALL, bool RELU, bool OUT_FLAG, bool BF_COPY>
__global__ __launch_bounds__(256) void gemm_kernel(
    const void* __restrict__ A0v, const void* __restrict__ A1v,
    const float* __restrict__ W0, const float* __restrict__ bias0,
    void* __restrict__ Cv, u16* __restrict__ Cbf, int M, int N, int K, int K0,
    const int* __restrict__ aflag, const int* __restrict__ oflag)
{
    __shared__ float As[16][68];
    __shared__ float Ws[16][68];
    const int tid = threadIdx.x;
    const int m0 = blockIdx.x * 64;
    const int n0 = blockIdx.y * 64;
    const int ty = tid >> 4, tx = tid & 15;
    const int lm = tid >> 2;          // 0..63
    const int k4 = (tid & 3) * 4;     // 0,4,8,12

    const bool a_bf16_rt = (aflag != nullptr) && (*aflag == 0);

    float acc[4][4] = {};

    for (int kc = 0; kc < K; kc += 16) {
        // --- A tile: As[k][m] ---
        {
            int gm = m0 + lm;
            float av0 = 0.f, av1 = 0.f, av2 = 0.f, av3 = 0.f;
            if (gm < M) {
                int kg = kc + k4;
                const void* Av = (DUAL_A && kg >= K0) ? A1v : A0v;
                int kl = (DUAL_A && kg >= K0) ? (kg - K0) : kg;
                int lda = DUAL_A ? ((kg >= K0) ? (K - K0) : K0) : K;
                if (A_BF16_ALL || (!DUAL_A && a_bf16_rt)) {
                    ushort4 u = *(const ushort4*)((const u16*)Av + (size_t)gm * lda + kl);
                    av0 = bf2f(u.x); av1 = bf2f(u.y); av2 = bf2f(u.z); av3 = bf2f(u.w);
                } else {
                    float4 f = *(const float4*)((const float*)Av + (size_t)gm * lda + kl);
                    av0 = f.x; av1 = f.y; av2 = f.z; av3 = f.w;
                }
            }
            As[k4 + 0][lm] = av0; As[k4 + 1][lm] = av1;
            As[k4 + 2][lm] = av2; As[k4 + 3][lm] = av3;
        }
        // --- W tile: Ws[k][n] ---
        {
            int gn = n0 + lm;            // N multiple of 64 -> no guard
            int kg = kc + k4;
            float4 f = *(const float4*)(W0 + (size_t)gn * K + kg);
            Ws[k4 + 0][lm] = f.x; Ws[k4 + 1][lm] = f.y;
            Ws[k4 + 2][lm] = f.z; Ws[k4 + 3][lm] = f.w;
        }
        __syncthreads();
        #pragma unroll
        for (int k = 0; k < 16; ++k) {
            float4 a = *(const float4*)&As[k][ty * 4];
            float4 b = *(const float4*)&Ws[k][tx * 4];
            float aa[4] = {a.x, a.y, a.z, a.w};
            float bb[4] = {b.x, b.y, b.z, b.w};
            #pragma unroll
            for (int i = 0; i < 4; ++i)
                #pragma unroll
                for (int j = 0; j < 4; ++j)
                    acc[i][j] += aa[i] * bb[j];
        }
        __syncthreads();
    }

    float bv[4];
    #pragma unroll
    for (int j = 0; j < 4; ++j) bv[j] = bias0[n0 + tx * 4 + j];

    const bool out_bf16 = OUT_FLAG && (*oflag == 0);

    #pragma unroll
    for (int i = 0; i < 4; ++i) {
        int gm = m0 + ty * 4 + i;
        if (gm >= M) continue;
        float o0 = acc[i][0] + bv[0], o1 = acc[i][1] + bv[1];
        float o2 = acc[i][2] + bv[2], o3 = acc[i][3] + bv[3];
        if (RELU) {
            o0 = fmaxf(o0, 0.f); o1 = fmaxf(o1, 0.f);
            o2 = fmaxf(o2, 0.f); o3 = fmaxf(o3, 0.f);
        }
        size_t co = (size_t)gm * N + n0 + tx * 4;
        if (out_bf16) {
            ushort4 u; u.x = f2bf(o0); u.y = f2bf(o1); u.z = f2bf(o2); u.w = f2bf(o3);
            *(ushort4*)((u16*)Cv + co) = u;
        } else {
            *(float4*)((float*)Cv + co) = make_float4(o0, o1, o2, o3);
        }
        if (BF_COPY) {
            ushort4 u; u.x = f2bf(o0); u.y = f2bf(o1); u.z = f2bf(o2); u.w = f2bf(o3);
            *(ushort4*)(Cbf + co) = u;
        }
    }
}

// ---------------------------------------------------------------------------
// MFMA fused LSTM step. Block = 32 rows (2 m-tiles), 4 waves.
// Wave w owns within-quadrant col slice q*128 + w*32 + [0,32) for q=0..3
// -> matched (i,f,g,o) accumulators per lane -> cell epilogue in registers.
// ---------------------------------------------------------------------------
template<bool HAS_H>
__global__ __launch_bounds__(256) void lstm_mfma_kernel(
    const u16* __restrict__ Xbf,     // [N_NODES][128] bf16
    const u16* __restrict__ hbf_in,  // prev h bf16 (HAS_H only)
    u16* __restrict__ hbf_out,       // h out bf16
    float* __restrict__ cf,          // c in/out f32 (HAS_H only)
    const u16* __restrict__ Wcat,    // [512][KK] bf16
    const float* __restrict__ bih, const float* __restrict__ bhh)
{
    constexpr int KK = HAS_H ? 256 : 128;
    const int w = threadIdx.x >> 6;
    const int l = threadIdx.x & 63;
    const int l15 = l & 15, quad = l >> 4;
    const int m0 = blockIdx.x * 32;
    const int kof = quad * 8;

    f32x4 acc[2][4][2] = {};   // [m-tile][gate-quadrant][n-subtile]

    const size_t rowA0 = (size_t)(m0 + l15) * HID + kof;
    const size_t rowA1 = (size_t)(m0 + 16 + l15) * HID + kof;

    #pragma unroll
    for (int kc = 0; kc < KK; kc += 32) {
        const u16* Ab = (HAS_H && kc >= 128) ? hbf_in : Xbf;
        int kl = (HAS_H && kc >= 128) ? (kc - 128) : kc;
        short8 a0 = *(const short8*)(Ab + rowA0 + kl);
        short8 a1 = *(const short8*)(Ab + rowA1 + kl);
        #pragma unroll
        for (int q = 0; q < 4; ++q) {
            #pragma unroll
            for (int t = 0; t < 2; ++t) {
                int n = q * 128 + w * 32 + t * 16 + l15;
                short8 b = *(const short8*)(Wcat + (size_t)n * KK + kc + kof);
                acc[0][q][t] = __builtin_amdgcn_mfma_f32_16x16x32_bf16(a0, b, acc[0][q][t], 0, 0, 0);
                acc[1][q][t] = __builtin_amdgcn_mfma_f32_16x16x32_bf16(a1, b, acc[1][q][t], 0, 0, 0);
            }
        }
    }

    // cell epilogue: C/D layout col = l&15, row = quad*4 + reg
    #pragma unroll
    for (int t = 0; t < 2; ++t) {
        int j = w * 32 + t * 16 + l15;
        float bI = bih[j]       + bhh[j];
        float bF = bih[128 + j] + bhh[128 + j];
        float bG = bih[256 + j] + bhh[256 + j];
        float bO = bih[384 + j] + bhh[384 + j];
        #pragma unroll
        for (int mt = 0; mt < 2; ++mt) {
            #pragma unroll
            for (int i = 0; i < 4; ++i) {
                int m = m0 + mt * 16 + quad * 4 + i;
                size_t off = (size_t)m * HID + j;
                float gi = sigm(acc[mt][0][t][i] + bI);
                float gf = sigm(acc[mt][1][t][i] + bF);
                float gg = tanh_fast(acc[mt][2][t][i] + bG);
                float go = sigm(acc[mt][3][t][i] + bO);
                float cn;
                if (HAS_H) {
                    cn = gf * cf[off] + gi * gg;
                    cf[off] = cn;
                } else {
                    cn = gi * gg;
                }
                hbf_out[off] = f2bf(go * tanh_fast(cn));
            }
        }
    }
}

// ---------------------------------------------------------------------------
// Wave step v3: one wave per node; lane holds float2 (feats 2*lane, 2*lane+1)
// -> ONE 512B gather instruction per edge (full f32 row). 4-edge unroll with
// independent accumulators: 4 gathers in flight per wave (latency-bound fix).
// ---------------------------------------------------------------------------
__global__ __launch_bounds__(256) void wave_kernel(
    const float* __restrict__ Xc, float* __restrict__ Xn, u16* __restrict__ Xnbf,
    float* __restrict__ Y, const float* __restrict__ degf,
    const int* __restrict__ rowptr, const int* __restrict__ csr)
{
    const int node = blockIdx.x * 4 + (threadIdx.x >> 6);
    if (node >= N_NODES) return;
    const int lane = threadIdx.x & 63;
    const int fo = lane * 2;

    const int beg = rowptr[node], end = rowptr[node + 1];
    float s0x = 0.f, s0y = 0.f, s1x = 0.f, s1y = 0.f;
    float s2x = 0.f, s2y = 0.f, s3x = 0.f, s3y = 0.f;

    int i = beg;
    for (; i + 4 <= end; i += 4) {
        int v0 = csr[i], v1 = csr[i + 1], v2 = csr[i + 2], v3 = csr[i + 3];
        float2 g0 = *(const float2*)(Xc + (size_t)v0 * HID + fo);
        float2 g1 = *(const float2*)(Xc + (size_t)v1 * HID + fo);
        float2 g2 = *(const float2*)(Xc + (size_t)v2 * HID + fo);
        float2 g3 = *(const float2*)(Xc + (size_t)v3 * HID + fo);
        s0x += g0.x; s0y += g0.y;
        s1x += g1.x; s1y += g1.y;
        s2x += g2.x; s2y += g2.y;
        s3x += g3.x; s3y += g3.y;
    }
    for (; i < end; ++i) {
        int v = csr[i];
        float2 g = *(const float2*)(Xc + (size_t)v * HID + fo);
        s0x += g.x; s0y += g.y;
    }
    float ax = (s0x + s1x) + (s2x + s3x);
    float ay = (s0y + s1y) + (s2y + s3y);

    const size_t off = (size_t)node * HID + fo;
    float2 xv = *(const float2*)(Xc + off);
    float2 yv = *(const float2*)(Y + off);
    float d = degf[node];
    float y0 = yv.x - HSTEP * (d * xv.x - ax);
    float y1 = yv.y - HSTEP * (d * xv.y - ay);
    *(float2*)(Y + off) = make_float2(y0, y1);
    float xn0 = xv.x + HSTEP * y0;
    float xn1 = xv.y + HSTEP * y1;
    *(float2*)(Xn + off) = make_float2(xn0, xn1);
    ushort2 ub; ub.x = f2bf(xn0); ub.y = f2bf(xn1);
    *(ushort2*)(Xnbf + off) = ub;
}

// ---------------------------------------------------------------------------
extern "C" void kernel_launch(void* const* d_in, const int* in_sizes, int n_in,
                              void* d_out, int out_size, void* d_ws, size_t ws_size,
                              hipStream_t stream)
{
    const void* x  = d_in[0];
    const int*  ei = (const int*)d_in[1];

    const size_t SZ_NH  = (size_t)N_NODES * HID * sizeof(float);   // 10,240,000
    const size_t SZ_NHB = (size_t)N_NODES * HID * sizeof(u16);     //  5,120,000
    const size_t SZ_I   = 80128;

    char* p = (char*)d_ws;
    float* Xa   = (float*)p; p += SZ_NH;
    float* Xb   = (float*)p; p += SZ_NH;
    float* Y    = (float*)p; p += SZ_NH;
    float* cf   = (float*)p; p += SZ_NH;
    u16*   hbf  = (u16*)p;   p += SZ_NHB;
    u16*   Xbf  = (u16*)p;   p += SZ_NHB;
    int*   deg  = (int*)p;   p += SZ_I;
    int*   fill = (int*)p;   p += SZ_I;
    int*   rowp = (int*)p;   p += SZ_I;
    float* degf = (float*)p; p += SZ_I;
    int*   csr  = (int*)p;   p += (size_t)N_EDGES * sizeof(int);
    int*   flag = (int*)p;   p += 128;
    float* wsf  = (float*)p; p += 272832 * sizeof(float);
    u16*   Wcat = (u16*)p;   p += 512 * 256 * sizeof(u16);
    u16*   Wb   = (u16*)p;   p += 512 * 128 * sizeof(u16);

    // converted f32 weight sub-pointers (offsets match cvt_off)
    float* Wenc1 = wsf + 0;
    float* benc1 = wsf + 16384;
    float* Wenc2 = wsf + 16512;
    float* benc2 = wsf + 32896;
    float* bihf  = wsf + 164096;
    float* bhhf  = wsf + 164608;
    float* bihb  = wsf + 230656;
    float* bhhb  = wsf + 231168;
    float* Wf1   = wsf + 231680;
    float* bf1   = wsf + 264448;
    float* Wf2   = wsf + 264576;
    float* bf2_  = wsf + 272768;

    float* H1   = Xb;        // encoder intermediate; Xb dead until wave t=1
    u16*   hbbf = (u16*)Y;   // backward h bf16; Y dead after last wave step

    hipMemsetAsync(Y, 0, 2 * SZ_NH + SZ_NHB, stream);   // Y, cf, hbf (contiguous)
    hipMemsetAsync(deg, 0, 2 * SZ_I, stream);           // deg, fill (contiguous)

    // dtype detect + weight conversion (f32 master, bf16 MFMA copies)
    detect_kernel<<<1, 256, 0, stream>>>((const u16*)x, flag);
    CvtArgs ca;
    ca.s[0] = d_in[2];  ca.s[1] = d_in[3];  ca.s[2] = d_in[4];  ca.s[3] = d_in[5];
    ca.s[4] = d_in[6];  ca.s[5] = d_in[7];  ca.s[6] = d_in[8];  ca.s[7] = d_in[9];
    ca.s[8] = d_in[10]; ca.s[9] = d_in[12]; ca.s[10] = d_in[13];
    ca.s[11] = d_in[14]; ca.s[12] = d_in[15]; ca.s[13] = d_in[16]; ca.s[14] = d_in[17];
    convert_kernel<<<(272832 + 255) / 256, 256, 0, stream>>>(ca, wsf, flag);
    build_wbf_kernel<<<512, 256, 0, stream>>>(wsf, Wcat, Wb);

    // CSR build
    count_kernel<<<(N_EDGES + 255) / 256, 256, 0, stream>>>(ei, deg);
    scan_kernel<<<1, 1024, 0, stream>>>(deg, rowp, degf);
    fill_kernel<<<(N_EDGES + 255) / 256, 256, 0, stream>>>(ei, rowp, fill, csr);

    const int MB = (N_NODES + 63) / 64;   // 313

    // encoder: H1 = relu(x @ Wenc1^T + b1); Xa = H1 @ Wenc2^T + b2 (+ bf16 copy)
    gemm_kernel<false, false, true, false, false><<<dim3(MB, 2), 256, 0, stream>>>(
        x, nullptr, Wenc1, benc1, H1, nullptr, N_NODES, HID, HID, HID, flag, nullptr);
    gemm_kernel<false, false, false, false, true><<<dim3(MB, 2), 256, 0, stream>>>(
        H1, nullptr, Wenc2, benc2, Xa, Xbf, N_NODES, HID, HID, HID, nullptr, nullptr);

    // wave scan interleaved with forward LSTM (MFMA fused gate-GEMM + cell)
    float* Xbuf[2] = {Xa, Xb};
    int cur = 0;
    for (int t = 0; t < NSTEPS; ++t) {
        if (t > 0) {
            wave_kernel<<<(N_NODES + 3) / 4, 256, 0, stream>>>(
                Xbuf[cur], Xbuf[1 - cur], Xbf, Y, degf, rowp, csr);
            cur ^= 1;
        }
        lstm_mfma_kernel<true><<<N_NODES / 32, 256, 0, stream>>>(
            Xbf, hbf, hbf, cf, Wcat, bihf, bhhf);
    }

    // backward LSTM: only hs_b[0] used -> one cell on X_tilde[15], zero state
    lstm_mfma_kernel<false><<<N_NODES / 32, 256, 0, stream>>>(
        Xbf, nullptr, hbbf, nullptr, Wb, bihb, bhhb);

    // head: F1 = relu([hbf | hbbf] @ Wf1^T + bf1); out = F1 @ Wf2^T + bf2
    float* F1 = Xbuf[1 - cur];   // dead X buffer
    gemm_kernel<true, true, true, false, false><<<dim3(MB, 2), 256, 0, stream>>>(
        hbf, hbbf, Wf1, bf1, F1, nullptr, N_NODES, HID, 2 * HID, HID, nullptr, nullptr);
    gemm_kernel<false, false, false, true, false><<<dim3(MB, 1), 256, 0, stream>>>(
        F1, nullptr, Wf2, bf2_, d_out, nullptr, N_NODES, OUT_DIM, HID, HID, nullptr, flag);
}

// Round 7
// 1386.255 us; speedup vs baseline: 1.8863x; 1.0999x over previous
//
#include <hip/hip_runtime.h>
#include <hip/hip_bf16.h>
#include <cstdint>
#include <cstddef>

#define N_NODES 20000
#define N_EDGES 640000
#define HID     128
#define OUT_DIM 64
#define NSTEPS  16
#define HSTEP   0.1f

typedef unsigned short u16;
typedef __attribute__((ext_vector_type(8))) short short8;   // 8 bf16 (4 VGPRs)
typedef __attribute__((ext_vector_type(4))) float f32x4;    // MFMA C/D

__device__ __forceinline__ float bf2f(u16 u) {
    union { unsigned int i; float f; } v; v.i = ((unsigned int)u) << 16; return v.f;
}
__device__ __forceinline__ u16 f2bf(float f) {
    union { float f; unsigned int i; } v; v.f = f;
    unsigned int x = v.i;
    unsigned int r = x + 0x7FFFu + ((x >> 16) & 1u);   // round-to-nearest-even
    return (u16)(r >> 16);
}

__device__ __forceinline__ float sigm(float x) { return 1.f / (1.f + __expf(-x)); }
__device__ __forceinline__ float tanh_fast(float x) {
    float e2 = __expf(-2.f * fabsf(x));
    float t = (1.f - e2) / (1.f + e2);
    return copysignf(t, x);
}

// ---------------------------------------------------------------------------
// Storage-dtype detection. flag=1 -> tensors stored as f32; flag=0 -> bf16.
// ---------------------------------------------------------------------------
__global__ void detect_kernel(const u16* __restrict__ xraw, int* __restrict__ flag) {
    __shared__ int cnt;
    if (threadIdx.x == 0) cnt = 0;
    __syncthreads();
    int c = 0;
    for (int i = threadIdx.x; i < 4096; i += 256) {
        int e = (xraw[i] >> 7) & 0xFF;
        if (e >= 0x90) c++;
    }
    atomicAdd(&cnt, c);
    __syncthreads();
    if (threadIdx.x == 0) *flag = (cnt > 100) ? 1 : 0;
}

// ---------------------------------------------------------------------------
// Packed conversion of the 15 weight/bias tensors into contiguous f32 ws.
// ---------------------------------------------------------------------------
#define N_CVT 15
struct CvtArgs { const void* s[N_CVT]; };
__constant__ const int cvt_off[N_CVT + 1] = {
    0, 16384, 16512, 32896, 33024, 98560, 164096, 164608, 165120,
    230656, 231168, 231680, 264448, 264576, 272768, 272832 };

__global__ void convert_kernel(CvtArgs a, float* __restrict__ dst,
                               const int* __restrict__ flag) {
    int i = blockIdx.x * blockDim.x + threadIdx.x;
    if (i >= 272832) return;
    int seg = 0;
    #pragma unroll
    for (int s = 1; s < N_CVT; ++s) if (i >= cvt_off[s]) seg = s;
    int j = i - cvt_off[seg];
    float v = (*flag) ? ((const float*)a.s[seg])[j]
                      : bf2f(((const u16*)a.s[seg])[j]);
    dst[i] = v;
}

// ---------------------------------------------------------------------------
// Build bf16 LSTM weights in MFMA B-fragment-swizzled order.
// Layout: elem (nt, ck, lane, j) = W[nt*16 + (lane&15)][ck*32 + (lane>>4)*8 + j]
// flat o = ((nt*NCK + ck)*64 + lane)*8 + j, NCK = KK/32.
// In-kernel B load becomes wave-uniform base + lane*16B -> fully coalesced.
// Forward: Wcat = [Wihf|Whhf], KK=256 (131072 elems). Backward: Wihb, KK=128.
// ---------------------------------------------------------------------------
__global__ void build_wswz_kernel(const float* __restrict__ wsf,
                                  u16* __restrict__ WswzF, u16* __restrict__ WswzB) {
    int o = blockIdx.x * blockDim.x + threadIdx.x;
    if (o < 131072) {   // forward, NCK=8
        int j = o & 7, l = (o >> 3) & 63, rest = o >> 9;
        int ck = rest & 7, nt = rest >> 3;
        int n = nt * 16 + (l & 15);
        int k = ck * 32 + (l >> 4) * 8 + j;
        const float* Wihf = wsf + 33024;
        const float* Whhf = wsf + 98560;
        float v = (k < 128) ? Wihf[n * 128 + k] : Whhf[n * 128 + (k - 128)];
        WswzF[o] = f2bf(v);
    }
    if (o < 65536) {    // backward, NCK=4
        int j = o & 7, l = (o >> 3) & 63, rest = o >> 9;
        int ck = rest & 3, nt = rest >> 2;
        int n = nt * 16 + (l & 15);
        int k = ck * 32 + (l >> 4) * 8 + j;
        const float* Wihb = wsf + 165120;
        WswzB[o] = f2bf(Wihb[n * 128 + k]);
    }
}

// ---------------------------------------------------------------------------
// CSR build: degree count -> exclusive scan -> bucket fill
// ---------------------------------------------------------------------------
__global__ void count_kernel(const int* __restrict__ ei, int* __restrict__ deg) {
    int e = blockIdx.x * blockDim.x + threadIdx.x;
    if (e < N_EDGES) atomicAdd(&deg[ei[N_EDGES + e]], 1);
}

__global__ __launch_bounds__(1024) void scan_kernel(const int* __restrict__ deg,
                                                    int* __restrict__ rowptr,
                                                    float* __restrict__ degf) {
    __shared__ int sd[1024];
    const int t = threadIdx.x;
    const int CH = (N_NODES + 1023) / 1024;   // 20
    int base = t * CH;
    int s = 0;
    for (int i = 0; i < CH; ++i) {
        int idx = base + i;
        if (idx < N_NODES) s += deg[idx];
    }
    sd[t] = s;
    __syncthreads();
    for (int off = 1; off < 1024; off <<= 1) {
        int v = (t >= off) ? sd[t - off] : 0;
        __syncthreads();
        sd[t] += v;
        __syncthreads();
    }
    int run = (t == 0) ? 0 : sd[t - 1];
    for (int i = 0; i < CH; ++i) {
        int idx = base + i;
        if (idx < N_NODES) {
            rowptr[idx] = run;
            degf[idx] = (float)deg[idx];
            run += deg[idx];
        }
    }
    if (t == 1023) rowptr[N_NODES] = sd[1023];
}

__global__ void fill_kernel(const int* __restrict__ ei, const int* __restrict__ rowptr,
                            int* __restrict__ fill, int* __restrict__ csr) {
    int e = blockIdx.x * blockDim.x + threadIdx.x;
    if (e < N_EDGES) {
        int d = ei[N_EDGES + e];
        int p = atomicAdd(&fill[d], 1);
        csr[rowptr[d] + p] = ei[e];
    }
}

// ---------------------------------------------------------------------------
// Tiled VALU GEMM (encoder + head): C[M,N] = A[M,K] @ W[N,K]^T + bias.
// DUAL_A: A=[A0|A1] split at K0. A_BF16_ALL: A halves stored bf16.
// aflag (runtime): non-dual A dtype follows detected storage (x input).
// OUT_FLAG: store f32/bf16 per *oflag. BF_COPY: also write bf16 copy to Cbf.
// ---------------------------------------------------------------------------
template<bool DUAL_A, bool A_BF16_ALL, bool RELU, bool OUT_FLAG, bool BF_COPY>
__global__ __launch_bounds__(256) void gemm_kernel(
    const void* __restrict__ A0v, const void* __restrict__ A1v,
    const float* __restrict__ W0, const float* __restrict__ bias0,
    void* __restrict__ Cv, u16* __restrict__ Cbf, int M, int N, int K, int K0,
    const int* __restrict__ aflag, const int* __restrict__ oflag)
{
    __shared__ float As[16][68];
    __shared__ float Ws[16][68];
    const int tid = threadIdx.x;
    const int m0 = blockIdx.x * 64;
    const int n0 = blockIdx.y * 64;
    const int ty = tid >> 4, tx = tid & 15;
    const int lm = tid >> 2;          // 0..63
    const int k4 = (tid & 3) * 4;     // 0,4,8,12

    const bool a_bf16_rt = (aflag != nullptr) && (*aflag == 0);

    float acc[4][4] = {};

    for (int kc = 0; kc < K; kc += 16) {
        // --- A tile: As[k][m] ---
        {
            int gm = m0 + lm;
            float av0 = 0.f, av1 = 0.f, av2 = 0.f, av3 = 0.f;
            if (gm < M) {
                int kg = kc + k4;
                const void* Av = (DUAL_A && kg >= K0) ? A1v : A0v;
                int kl = (DUAL_A && kg >= K0) ? (kg - K0) : kg;
                int lda = DUAL_A ? ((kg >= K0) ? (K - K0) : K0) : K;
                if (A_BF16_ALL || (!DUAL_A && a_bf16_rt)) {
                    ushort4 u = *(const ushort4*)((const u16*)Av + (size_t)gm * lda + kl);
                    av0 = bf2f(u.x); av1 = bf2f(u.y); av2 = bf2f(u.z); av3 = bf2f(u.w);
                } else {
                    float4 f = *(const float4*)((const float*)Av + (size_t)gm * lda + kl);
                    av0 = f.x; av1 = f.y; av2 = f.z; av3 = f.w;
                }
            }
            As[k4 + 0][lm] = av0; As[k4 + 1][lm] = av1;
            As[k4 + 2][lm] = av2; As[k4 + 3][lm] = av3;
        }
        // --- W tile: Ws[k][n] ---
        {
            int gn = n0 + lm;            // N multiple of 64 -> no guard
            int kg = kc + k4;
            float4 f = *(const float4*)(W0 + (size_t)gn * K + kg);
            Ws[k4 + 0][lm] = f.x; Ws[k4 + 1][lm] = f.y;
            Ws[k4 + 2][lm] = f.z; Ws[k4 + 3][lm] = f.w;
        }
        __syncthreads();
        #pragma unroll
        for (int k = 0; k < 16; ++k) {
            float4 a = *(const float4*)&As[k][ty * 4];
            float4 b = *(const float4*)&Ws[k][tx * 4];
            float aa[4] = {a.x, a.y, a.z, a.w};
            float bb[4] = {b.x, b.y, b.z, b.w};
            #pragma unroll
            for (int i = 0; i < 4; ++i)
                #pragma unroll
                for (int j = 0; j < 4; ++j)
                    acc[i][j] += aa[i] * bb[j];
        }
        __syncthreads();
    }

    float bv[4];
    #pragma unroll
    for (int j = 0; j < 4; ++j) bv[j] = bias0[n0 + tx * 4 + j];

    const bool out_bf16 = OUT_FLAG && (*oflag == 0);

    #pragma unroll
    for (int i = 0; i < 4; ++i) {
        int gm = m0 + ty * 4 + i;
        if (gm >= M) continue;
        float o0 = acc[i][0] + bv[0], o1 = acc[i][1] + bv[1];
        float o2 = acc[i][2] + bv[2], o3 = acc[i][3] + bv[3];
        if (RELU) {
            o0 = fmaxf(o0, 0.f); o1 = fmaxf(o1, 0.f);
            o2 = fmaxf(o2, 0.f); o3 = fmaxf(o3, 0.f);
        }
        size_t co = (size_t)gm * N + n0 + tx * 4;
        if (out_bf16) {
            ushort4 u; u.x = f2bf(o0); u.y = f2bf(o1); u.z = f2bf(o2); u.w = f2bf(o3);
            *(ushort4*)((u16*)Cv + co) = u;
        } else {
            *(float4*)((float*)Cv + co) = make_float4(o0, o1, o2, o3);
        }
        if (BF_COPY) {
            ushort4 u; u.x = f2bf(o0); u.y = f2bf(o1); u.z = f2bf(o2); u.w = f2bf(o3);
            *(ushort4*)(Cbf + co) = u;
        }
    }
}

// ---------------------------------------------------------------------------
// MFMA fused LSTM step. Block = 32 rows (2 m-tiles), 4 waves.
// Wave w owns within-quadrant col slice q*128 + w*32 + [0,32) for q=0..3
// -> matched (i,f,g,o) accumulators per lane -> cell epilogue in registers.
// B loads from fragment-swizzled Wswz: wave-uniform base + lane*16B.
// ---------------------------------------------------------------------------
template<bool HAS_H>
__global__ __launch_bounds__(256) void lstm_mfma_kernel(
    const u16* __restrict__ Xbf,     // [N_NODES][128] bf16
    const u16* __restrict__ hbf_in,  // prev h bf16 (HAS_H only)
    u16* __restrict__ hbf_out,       // h out bf16
    float* __restrict__ cf,          // c in/out f32 (HAS_H only)
    const u16* __restrict__ Wswz,    // fragment-swizzled [32 nt][NCK][64][8]
    const float* __restrict__ bih, const float* __restrict__ bhh)
{
    constexpr int KK = HAS_H ? 256 : 128;
    constexpr int NCK = KK / 32;
    const int w = threadIdx.x >> 6;
    const int l = threadIdx.x & 63;
    const int l15 = l & 15, quad = l >> 4;
    const int m0 = blockIdx.x * 32;
    const int kof = quad * 8;

    f32x4 acc[2][4][2] = {};   // [m-tile][gate-quadrant][n-subtile]

    const size_t rowA0 = (size_t)(m0 + l15) * HID + kof;
    const size_t rowA1 = (size_t)(m0 + 16 + l15) * HID + kof;

    #pragma unroll
    for (int kc = 0; kc < KK; kc += 32) {
        const int ck = kc >> 5;
        const u16* Ab = (HAS_H && kc >= 128) ? hbf_in : Xbf;
        int kl = (HAS_H && kc >= 128) ? (kc - 128) : kc;
        short8 a0 = *(const short8*)(Ab + rowA0 + kl);
        short8 a1 = *(const short8*)(Ab + rowA1 + kl);
        #pragma unroll
        for (int q = 0; q < 4; ++q) {
            #pragma unroll
            for (int t = 0; t < 2; ++t) {
                int nt = q * 8 + w * 2 + t;          // n-tile = n/16
                short8 b = *(const short8*)(Wswz + (((size_t)(nt * NCK + ck)) << 9) + (l << 3));
                acc[0][q][t] = __builtin_amdgcn_mfma_f32_16x16x32_bf16(a0, b, acc[0][q][t], 0, 0, 0);
                acc[1][q][t] = __builtin_amdgcn_mfma_f32_16x16x32_bf16(a1, b, acc[1][q][t], 0, 0, 0);
            }
        }
    }

    // cell epilogue: C/D layout col = l&15, row = quad*4 + reg
    #pragma unroll
    for (int t = 0; t < 2; ++t) {
        int j = w * 32 + t * 16 + l15;
        float bI = bih[j]       + bhh[j];
        float bF = bih[128 + j] + bhh[128 + j];
        float bG = bih[256 + j] + bhh[256 + j];
        float bO = bih[384 + j] + bhh[384 + j];
        #pragma unroll
        for (int mt = 0; mt < 2; ++mt) {
            #pragma unroll
            for (int i = 0; i < 4; ++i) {
                int m = m0 + mt * 16 + quad * 4 + i;
                size_t off = (size_t)m * HID + j;
                float gi = sigm(acc[mt][0][t][i] + bI);
                float gf = sigm(acc[mt][1][t][i] + bF);
                float gg = tanh_fast(acc[mt][2][t][i] + bG);
                float go = sigm(acc[mt][3][t][i] + bO);
                float cn;
                if (HAS_H) {
                    cn = gf * cf[off] + gi * gg;
                    cf[off] = cn;
                } else {
                    cn = gi * gg;
                }
                hbf_out[off] = f2bf(go * tanh_fast(cn));
            }
        }
    }
}

// ---------------------------------------------------------------------------
// Wave step v3: one wave per node; lane holds float2 (feats 2*lane, 2*lane+1)
// -> ONE 512B gather instruction per edge (full f32 row). 4-edge unroll with
// independent accumulators: 4 gathers in flight per wave (latency-bound fix).
// ---------------------------------------------------------------------------
__global__ __launch_bounds__(256) void wave_kernel(
    const float* __restrict__ Xc, float* __restrict__ Xn, u16* __restrict__ Xnbf,
    float* __restrict__ Y, const float* __restrict__ degf,
    const int* __restrict__ rowptr, const int* __restrict__ csr)
{
    const int node = blockIdx.x * 4 + (threadIdx.x >> 6);
    if (node >= N_NODES) return;
    const int lane = threadIdx.x & 63;
    const int fo = lane * 2;

    const int beg = rowptr[node], end = rowptr[node + 1];
    float s0x = 0.f, s0y = 0.f, s1x = 0.f, s1y = 0.f;
    float s2x = 0.f, s2y = 0.f, s3x = 0.f, s3y = 0.f;

    int i = beg;
    for (; i + 4 <= end; i += 4) {
        int v0 = csr[i], v1 = csr[i + 1], v2 = csr[i + 2], v3 = csr[i + 3];
        float2 g0 = *(const float2*)(Xc + (size_t)v0 * HID + fo);
        float2 g1 = *(const float2*)(Xc + (size_t)v1 * HID + fo);
        float2 g2 = *(const float2*)(Xc + (size_t)v2 * HID + fo);
        float2 g3 = *(const float2*)(Xc + (size_t)v3 * HID + fo);
        s0x += g0.x; s0y += g0.y;
        s1x += g1.x; s1y += g1.y;
        s2x += g2.x; s2y += g2.y;
        s3x += g3.x; s3y += g3.y;
    }
    for (; i < end; ++i) {
        int v = csr[i];
        float2 g = *(const float2*)(Xc + (size_t)v * HID + fo);
        s0x += g.x; s0y += g.y;
    }
    float ax = (s0x + s1x) + (s2x + s3x);
    float ay = (s0y + s1y) + (s2y + s3y);

    const size_t off = (size_t)node * HID + fo;
    float2 xv = *(const float2*)(Xc + off);
    float2 yv = *(const float2*)(Y + off);
    float d = degf[node];
    float y0 = yv.x - HSTEP * (d * xv.x - ax);
    float y1 = yv.y - HSTEP * (d * xv.y - ay);
    *(float2*)(Y + off) = make_float2(y0, y1);
    float xn0 = xv.x + HSTEP * y0;
    float xn1 = xv.y + HSTEP * y1;
    *(float2*)(Xn + off) = make_float2(xn0, xn1);
    ushort2 ub; ub.x = f2bf(xn0); ub.y = f2bf(xn1);
    *(ushort2*)(Xnbf + off) = ub;
}

// ---------------------------------------------------------------------------
extern "C" void kernel_launch(void* const* d_in, const int* in_sizes, int n_in,
                              void* d_out, int out_size, void* d_ws, size_t ws_size,
                              hipStream_t stream)
{
    const void* x  = d_in[0];
    const int*  ei = (const int*)d_in[1];

    const size_t SZ_NH  = (size_t)N_NODES * HID * sizeof(float);   // 10,240,000
    const size_t SZ_NHB = (size_t)N_NODES * HID * sizeof(u16);     //  5,120,000
    const size_t SZ_I   = 80128;

    char* p = (char*)d_ws;
    float* Xa   = (float*)p; p += SZ_NH;
    float* Xb   = (float*)p; p += SZ_NH;
    float* Y    = (float*)p; p += SZ_NH;
    float* cf   = (float*)p; p += SZ_NH;
    u16*   hbf  = (u16*)p;   p += SZ_NHB;
    u16*   Xbf  = (u16*)p;   p += SZ_NHB;
    int*   deg  = (int*)p;   p += SZ_I;
    int*   fill = (int*)p;   p += SZ_I;
    int*   rowp = (int*)p;   p += SZ_I;
    float* degf = (float*)p; p += SZ_I;
    int*   csr  = (int*)p;   p += (size_t)N_EDGES * sizeof(int);
    int*   flag = (int*)p;   p += 128;
    float* wsf  = (float*)p; p += 272832 * sizeof(float);
    u16*   WswzF = (u16*)p;  p += 131072 * sizeof(u16);
    u16*   WswzB = (u16*)p;  p += 65536 * sizeof(u16);

    // converted f32 weight sub-pointers (offsets match cvt_off)
    float* Wenc1 = wsf + 0;
    float* benc1 = wsf + 16384;
    float* Wenc2 = wsf + 16512;
    float* benc2 = wsf + 32896;
    float* bihf  = wsf + 164096;
    float* bhhf  = wsf + 164608;
    float* bihb  = wsf + 230656;
    float* bhhb  = wsf + 231168;
    float* Wf1   = wsf + 231680;
    float* bf1   = wsf + 264448;
    float* Wf2   = wsf + 264576;
    float* bf2_  = wsf + 272768;

    float* H1   = Xb;        // encoder intermediate; Xb dead until wave t=1
    u16*   hbbf = (u16*)Y;   // backward h bf16; Y dead after last wave step

    hipMemsetAsync(Y, 0, 2 * SZ_NH + SZ_NHB, stream);   // Y, cf, hbf (contiguous)
    hipMemsetAsync(deg, 0, 2 * SZ_I, stream);           // deg, fill (contiguous)

    // dtype detect + weight conversion (f32 master, swizzled bf16 MFMA copies)
    detect_kernel<<<1, 256, 0, stream>>>((const u16*)x, flag);
    CvtArgs ca;
    ca.s[0] = d_in[2];  ca.s[1] = d_in[3];  ca.s[2] = d_in[4];  ca.s[3] = d_in[5];
    ca.s[4] = d_in[6];  ca.s[5] = d_in[7];  ca.s[6] = d_in[8];  ca.s[7] = d_in[9];
    ca.s[8] = d_in[10]; ca.s[9] = d_in[12]; ca.s[10] = d_in[13];
    ca.s[11] = d_in[14]; ca.s[12] = d_in[15]; ca.s[13] = d_in[16]; ca.s[14] = d_in[17];
    convert_kernel<<<(272832 + 255) / 256, 256, 0, stream>>>(ca, wsf, flag);
    build_wswz_kernel<<<512, 256, 0, stream>>>(wsf, WswzF, WswzB);

    // CSR build
    count_kernel<<<(N_EDGES + 255) / 256, 256, 0, stream>>>(ei, deg);
    scan_kernel<<<1, 1024, 0, stream>>>(deg, rowp, degf);
    fill_kernel<<<(N_EDGES + 255) / 256, 256, 0, stream>>>(ei, rowp, fill, csr);

    const int MB = (N_NODES + 63) / 64;   // 313

    // encoder: H1 = relu(x @ Wenc1^T + b1); Xa = H1 @ Wenc2^T + b2 (+ bf16 copy)
    gemm_kernel<false, false, true, false, false><<<dim3(MB, 2), 256, 0, stream>>>(
        x, nullptr, Wenc1, benc1, H1, nullptr, N_NODES, HID, HID, HID, flag, nullptr);
    gemm_kernel<false, false, false, false, true><<<dim3(MB, 2), 256, 0, stream>>>(
        H1, nullptr, Wenc2, benc2, Xa, Xbf, N_NODES, HID, HID, HID, nullptr, nullptr);

    // wave scan interleaved with forward LSTM (MFMA fused gate-GEMM + cell)
    float* Xbuf[2] = {Xa, Xb};
    int cur = 0;
    for (int t = 0; t < NSTEPS; ++t) {
        if (t > 0) {
            wave_kernel<<<(N_NODES + 3) / 4, 256, 0, stream>>>(
                Xbuf[cur], Xbuf[1 - cur], Xbf, Y, degf, rowp, csr);
            cur ^= 1;
        }
        lstm_mfma_kernel<true><<<N_NODES / 32, 256, 0, stream>>>(
            Xbf, hbf, hbf, cf, WswzF, bihf, bhhf);
    }

    // backward LSTM: only hs_b[0] used -> one cell on X_tilde[15], zero state
    lstm_mfma_kernel<false><<<N_NODES / 32, 256, 0, stream>>>(
        Xbf, nullptr, hbbf, nullptr, WswzB, bihb, bhhb);

    // head: F1 = relu([hbf | hbbf] @ Wf1^T + bf1); out = F1 @ Wf2^T + bf2
    float* F1 = Xbuf[1 - cur];   // dead X buffer
    gemm_kernel<true, true, true, false, false><<<dim3(MB, 2), 256, 0, stream>>>(
        hbf, hbbf, Wf1, bf1, F1, nullptr, N_NODES, HID, 2 * HID, HID, nullptr, nullptr);
    gemm_kernel<false, false, false, true, false><<<dim3(MB, 1), 256, 0, stream>>>(
        F1, nullptr, Wf2, bf2_, d_out, nullptr, N_NODES, OUT_DIM, HID, HID, nullptr, flag);
}

// Round 8
// 1114.306 us; speedup vs baseline: 2.3466x; 1.2441x over previous
//
#include <hip/hip_runtime.h>
#include <hip/hip_bf16.h>
#include <cstdint>
#include <cstddef>

#define N_NODES 20000
#define N_EDGES 640000
#define HID     128
#define OUT_DIM 64
#define NSTEPS  16
#define HSTEP   0.1f

typedef unsigned short u16;
typedef __attribute__((ext_vector_type(8))) short short8;   // 8 bf16 (4 VGPRs)
typedef __attribute__((ext_vector_type(4))) float f32x4;    // MFMA C/D

__device__ __forceinline__ float bf2f(u16 u) {
    union { unsigned int i; float f; } v; v.i = ((unsigned int)u) << 16; return v.f;
}
__device__ __forceinline__ u16 f2bf(float f) {
    union { float f; unsigned int i; } v; v.f = f;
    unsigned int x = v.i;
    unsigned int r = x + 0x7FFFu + ((x >> 16) & 1u);   // round-to-nearest-even
    return (u16)(r >> 16);
}

__device__ __forceinline__ float sigm(float x) { return 1.f / (1.f + __expf(-x)); }
__device__ __forceinline__ float tanh_fast(float x) {
    float e2 = __expf(-2.f * fabsf(x));
    float t = (1.f - e2) / (1.f + e2);
    return copysignf(t, x);
}

// ---------------------------------------------------------------------------
// Storage-dtype detection. flag=1 -> tensors stored as f32; flag=0 -> bf16.
// ---------------------------------------------------------------------------
__global__ void detect_kernel(const u16* __restrict__ xraw, int* __restrict__ flag) {
    __shared__ int cnt;
    if (threadIdx.x == 0) cnt = 0;
    __syncthreads();
    int c = 0;
    for (int i = threadIdx.x; i < 4096; i += 256) {
        int e = (xraw[i] >> 7) & 0xFF;
        if (e >= 0x90) c++;
    }
    atomicAdd(&cnt, c);
    __syncthreads();
    if (threadIdx.x == 0) *flag = (cnt > 100) ? 1 : 0;
}

// ---------------------------------------------------------------------------
// Packed conversion of the 15 weight/bias tensors into contiguous f32 ws.
// ---------------------------------------------------------------------------
#define N_CVT 15
struct CvtArgs { const void* s[N_CVT]; };
__constant__ const int cvt_off[N_CVT + 1] = {
    0, 16384, 16512, 32896, 33024, 98560, 164096, 164608, 165120,
    230656, 231168, 231680, 264448, 264576, 272768, 272832 };

__global__ void convert_kernel(CvtArgs a, float* __restrict__ dst,
                               const int* __restrict__ flag) {
    int i = blockIdx.x * blockDim.x + threadIdx.x;
    if (i >= 272832) return;
    int seg = 0;
    #pragma unroll
    for (int s = 1; s < N_CVT; ++s) if (i >= cvt_off[s]) seg = s;
    int j = i - cvt_off[seg];
    float v = (*flag) ? ((const float*)a.s[seg])[j]
                      : bf2f(((const u16*)a.s[seg])[j]);
    dst[i] = v;
}

// ---------------------------------------------------------------------------
// Build bf16 LSTM weights in MFMA B-fragment-swizzled order.
// elem (nt, ck, lane, j) = W[nt*16 + (lane&15)][ck*32 + (lane>>4)*8 + j]
// flat o = ((nt*NCK + ck)*64 + lane)*8 + j, NCK = KK/32.
// ---------------------------------------------------------------------------
__global__ void build_wswz_kernel(const float* __restrict__ wsf,
                                  u16* __restrict__ WswzF, u16* __restrict__ WswzB) {
    int o = blockIdx.x * blockDim.x + threadIdx.x;
    if (o < 131072) {   // forward, NCK=8
        int j = o & 7, l = (o >> 3) & 63, rest = o >> 9;
        int ck = rest & 7, nt = rest >> 3;
        int n = nt * 16 + (l & 15);
        int k = ck * 32 + (l >> 4) * 8 + j;
        const float* Wihf = wsf + 33024;
        const float* Whhf = wsf + 98560;
        float v = (k < 128) ? Wihf[n * 128 + k] : Whhf[n * 128 + (k - 128)];
        WswzF[o] = f2bf(v);
    }
    if (o < 65536) {    // backward, NCK=4
        int j = o & 7, l = (o >> 3) & 63, rest = o >> 9;
        int ck = rest & 3, nt = rest >> 2;
        int n = nt * 16 + (l & 15);
        int k = ck * 32 + (l >> 4) * 8 + j;
        const float* Wihb = wsf + 165120;
        WswzB[o] = f2bf(Wihb[n * 128 + k]);
    }
}

// ---------------------------------------------------------------------------
// CSR build: degree count -> exclusive scan -> bucket fill
// ---------------------------------------------------------------------------
__global__ void count_kernel(const int* __restrict__ ei, int* __restrict__ deg) {
    int e = blockIdx.x * blockDim.x + threadIdx.x;
    if (e < N_EDGES) atomicAdd(&deg[ei[N_EDGES + e]], 1);
}

__global__ __launch_bounds__(1024) void scan_kernel(const int* __restrict__ deg,
                                                    int* __restrict__ rowptr,
                                                    float* __restrict__ degf) {
    __shared__ int sd[1024];
    const int t = threadIdx.x;
    const int CH = (N_NODES + 1023) / 1024;   // 20
    int base = t * CH;
    int s = 0;
    for (int i = 0; i < CH; ++i) {
        int idx = base + i;
        if (idx < N_NODES) s += deg[idx];
    }
    sd[t] = s;
    __syncthreads();
    for (int off = 1; off < 1024; off <<= 1) {
        int v = (t >= off) ? sd[t - off] : 0;
        __syncthreads();
        sd[t] += v;
        __syncthreads();
    }
    int run = (t == 0) ? 0 : sd[t - 1];
    for (int i = 0; i < CH; ++i) {
        int idx = base + i;
        if (idx < N_NODES) {
            rowptr[idx] = run;
            degf[idx] = (float)deg[idx];
            run += deg[idx];
        }
    }
    if (t == 1023) rowptr[N_NODES] = sd[1023];
}

__global__ void fill_kernel(const int* __restrict__ ei, const int* __restrict__ rowptr,
                            int* __restrict__ fill, int* __restrict__ csr) {
    int e = blockIdx.x * blockDim.x + threadIdx.x;
    if (e < N_EDGES) {
        int d = ei[N_EDGES + e];
        int p = atomicAdd(&fill[d], 1);
        csr[rowptr[d] + p] = ei[e];
    }
}

// ---------------------------------------------------------------------------
// Tiled VALU GEMM (encoder + head): C[M,N] = A[M,K] @ W[N,K]^T + bias.
// ---------------------------------------------------------------------------
template<bool DUAL_A, bool A_BF16_ALL, bool RELU, bool OUT_FLAG, bool BF_COPY>
__global__ __launch_bounds__(256) void gemm_kernel(
    const void* __restrict__ A0v, const void* __restrict__ A1v,
    const float* __restrict__ W0, const float* __restrict__ bias0,
    void* __restrict__ Cv, u16* __restrict__ Cbf, int M, int N, int K, int K0,
    const int* __restrict__ aflag, const int* __restrict__ oflag)
{
    __shared__ float As[16][68];
    __shared__ float Ws[16][68];
    const int tid = threadIdx.x;
    const int m0 = blockIdx.x * 64;
    const int n0 = blockIdx.y * 64;
    const int ty = tid >> 4, tx = tid & 15;
    const int lm = tid >> 2;          // 0..63
    const int k4 = (tid & 3) * 4;     // 0,4,8,12

    const bool a_bf16_rt = (aflag != nullptr) && (*aflag == 0);

    float acc[4][4] = {};

    for (int kc = 0; kc < K; kc += 16) {
        {
            int gm = m0 + lm;
            float av0 = 0.f, av1 = 0.f, av2 = 0.f, av3 = 0.f;
            if (gm < M) {
                int kg = kc + k4;
                const void* Av = (DUAL_A && kg >= K0) ? A1v : A0v;
                int kl = (DUAL_A && kg >= K0) ? (kg - K0) : kg;
                int lda = DUAL_A ? ((kg >= K0) ? (K - K0) : K0) : K;
                if (A_BF16_ALL || (!DUAL_A && a_bf16_rt)) {
                    ushort4 u = *(const ushort4*)((const u16*)Av + (size_t)gm * lda + kl);
                    av0 = bf2f(u.x); av1 = bf2f(u.y); av2 = bf2f(u.z); av3 = bf2f(u.w);
                } else {
                    float4 f = *(const float4*)((const float*)Av + (size_t)gm * lda + kl);
                    av0 = f.x; av1 = f.y; av2 = f.z; av3 = f.w;
                }
            }
            As[k4 + 0][lm] = av0; As[k4 + 1][lm] = av1;
            As[k4 + 2][lm] = av2; As[k4 + 3][lm] = av3;
        }
        {
            int gn = n0 + lm;
            int kg = kc + k4;
            float4 f = *(const float4*)(W0 + (size_t)gn * K + kg);
            Ws[k4 + 0][lm] = f.x; Ws[k4 + 1][lm] = f.y;
            Ws[k4 + 2][lm] = f.z; Ws[k4 + 3][lm] = f.w;
        }
        __syncthreads();
        #pragma unroll
        for (int k = 0; k < 16; ++k) {
            float4 a = *(const float4*)&As[k][ty * 4];
            float4 b = *(const float4*)&Ws[k][tx * 4];
            float aa[4] = {a.x, a.y, a.z, a.w};
            float bb[4] = {b.x, b.y, b.z, b.w};
            #pragma unroll
            for (int i = 0; i < 4; ++i)
                #pragma unroll
                for (int j = 0; j < 4; ++j)
                    acc[i][j] += aa[i] * bb[j];
        }
        __syncthreads();
    }

    float bv[4];
    #pragma unroll
    for (int j = 0; j < 4; ++j) bv[j] = bias0[n0 + tx * 4 + j];

    const bool out_bf16 = OUT_FLAG && (*oflag == 0);

    #pragma unroll
    for (int i = 0; i < 4; ++i) {
        int gm = m0 + ty * 4 + i;
        if (gm >= M) continue;
        float o0 = acc[i][0] + bv[0], o1 = acc[i][1] + bv[1];
        float o2 = acc[i][2] + bv[2], o3 = acc[i][3] + bv[3];
        if (RELU) {
            o0 = fmaxf(o0, 0.f); o1 = fmaxf(o1, 0.f);
            o2 = fmaxf(o2, 0.f); o3 = fmaxf(o3, 0.f);
        }
        size_t co = (size_t)gm * N + n0 + tx * 4;
        if (out_bf16) {
            ushort4 u; u.x = f2bf(o0); u.y = f2bf(o1); u.z = f2bf(o2); u.w = f2bf(o3);
            *(ushort4*)((u16*)Cv + co) = u;
        } else {
            *(float4*)((float*)Cv + co) = make_float4(o0, o1, o2, o3);
        }
        if (BF_COPY) {
            ushort4 u; u.x = f2bf(o0); u.y = f2bf(o1); u.z = f2bf(o2); u.w = f2bf(o3);
            *(ushort4*)(Cbf + co) = u;
        }
    }
}

// ---------------------------------------------------------------------------
// MFMA fused LSTM step. Block = 32 rows, 512 threads / 8 waves.
// Wave w owns within-quadrant col slice q*128 + w*16 + [0,16) for q=0..3
// (nt = q*8 + w) -> matched (i,f,g,o) per lane, cell epilogue in registers.
// 8 waves/block, grid 625 -> ~4.9 waves/SIMD for latency hiding.
// B loads from fragment-swizzled Wswz: wave-uniform base + lane*16B.
// ---------------------------------------------------------------------------
template<bool HAS_H>
__global__ __launch_bounds__(512) void lstm_mfma_kernel(
    const u16* __restrict__ Xbf,     // [N_NODES][128] bf16
    const u16* __restrict__ hbf_in,  // prev h bf16 (HAS_H only)
    u16* __restrict__ hbf_out,       // h out bf16
    float* __restrict__ cf,          // c in/out f32 (HAS_H only)
    const u16* __restrict__ Wswz,    // fragment-swizzled [32 nt][NCK][64][8]
    const float* __restrict__ bih, const float* __restrict__ bhh)
{
    constexpr int KK = HAS_H ? 256 : 128;
    constexpr int NCK = KK / 32;
    const int w = threadIdx.x >> 6;          // 0..7
    const int l = threadIdx.x & 63;
    const int l15 = l & 15, quad = l >> 4;
    const int m0 = blockIdx.x * 32;
    const int kof = quad * 8;

    f32x4 acc[2][4] = {};   // [m-tile][gate-quadrant]

    const size_t rowA0 = (size_t)(m0 + l15) * HID + kof;
    const size_t rowA1 = (size_t)(m0 + 16 + l15) * HID + kof;

    #pragma unroll
    for (int kc = 0; kc < KK; kc += 32) {
        const int ck = kc >> 5;
        const u16* Ab = (HAS_H && kc >= 128) ? hbf_in : Xbf;
        int kl = (HAS_H && kc >= 128) ? (kc - 128) : kc;
        short8 a0 = *(const short8*)(Ab + rowA0 + kl);
        short8 a1 = *(const short8*)(Ab + rowA1 + kl);
        #pragma unroll
        for (int q = 0; q < 4; ++q) {
            int nt = q * 8 + w;
            short8 b = *(const short8*)(Wswz + (((size_t)(nt * NCK + ck)) << 9) + (l << 3));
            acc[0][q] = __builtin_amdgcn_mfma_f32_16x16x32_bf16(a0, b, acc[0][q], 0, 0, 0);
            acc[1][q] = __builtin_amdgcn_mfma_f32_16x16x32_bf16(a1, b, acc[1][q], 0, 0, 0);
        }
    }

    // cell epilogue: C/D layout col = l&15, row = quad*4 + reg
    const int j = w * 16 + l15;
    const float bI = bih[j]       + bhh[j];
    const float bF = bih[128 + j] + bhh[128 + j];
    const float bG = bih[256 + j] + bhh[256 + j];
    const float bO = bih[384 + j] + bhh[384 + j];
    #pragma unroll
    for (int mt = 0; mt < 2; ++mt) {
        #pragma unroll
        for (int i = 0; i < 4; ++i) {
            int m = m0 + mt * 16 + quad * 4 + i;
            size_t off = (size_t)m * HID + j;
            float gi = sigm(acc[mt][0][i] + bI);
            float gf = sigm(acc[mt][1][i] + bF);
            float gg = tanh_fast(acc[mt][2][i] + bG);
            float go = sigm(acc[mt][3][i] + bO);
            float cn;
            if (HAS_H) {
                cn = gf * cf[off] + gi * gg;
                cf[off] = cn;
            } else {
                cn = gi * gg;
            }
            hbf_out[off] = f2bf(go * tanh_fast(cn));
        }
    }
}

// ---------------------------------------------------------------------------
// Wave step v4: one wave per node; gather from bf16 XbfP (256B/edge, one u32
// per lane), self/recursion terms f32. 4-edge unroll for MLP. Writes f32 Xn
// (recursion), bf16 XbfN (next gather + LSTM input; double-buffered).
// ---------------------------------------------------------------------------
__global__ __launch_bounds__(256) void wave_kernel(
    const float* __restrict__ Xc, float* __restrict__ Xn,
    const u16* __restrict__ XbfP, u16* __restrict__ XbfN,
    float* __restrict__ Y, const float* __restrict__ degf,
    const int* __restrict__ rowptr, const int* __restrict__ csr)
{
    const int node = blockIdx.x * 4 + (threadIdx.x >> 6);
    if (node >= N_NODES) return;
    const int lane = threadIdx.x & 63;
    const int fo = lane * 2;

    const int beg = rowptr[node], end = rowptr[node + 1];
    float s0x = 0.f, s0y = 0.f, s1x = 0.f, s1y = 0.f;
    float s2x = 0.f, s2y = 0.f, s3x = 0.f, s3y = 0.f;

    int i = beg;
    for (; i + 4 <= end; i += 4) {
        int v0 = csr[i], v1 = csr[i + 1], v2 = csr[i + 2], v3 = csr[i + 3];
        ushort2 g0 = *(const ushort2*)(XbfP + (size_t)v0 * HID + fo);
        ushort2 g1 = *(const ushort2*)(XbfP + (size_t)v1 * HID + fo);
        ushort2 g2 = *(const ushort2*)(XbfP + (size_t)v2 * HID + fo);
        ushort2 g3 = *(const ushort2*)(XbfP + (size_t)v3 * HID + fo);
        s0x += bf2f(g0.x); s0y += bf2f(g0.y);
        s1x += bf2f(g1.x); s1y += bf2f(g1.y);
        s2x += bf2f(g2.x); s2y += bf2f(g2.y);
        s3x += bf2f(g3.x); s3y += bf2f(g3.y);
    }
    for (; i < end; ++i) {
        int v = csr[i];
        ushort2 g = *(const ushort2*)(XbfP + (size_t)v * HID + fo);
        s0x += bf2f(g.x); s0y += bf2f(g.y);
    }
    float ax = (s0x + s1x) + (s2x + s3x);
    float ay = (s0y + s1y) + (s2y + s3y);

    const size_t off = (size_t)node * HID + fo;
    float2 xv = *(const float2*)(Xc + off);
    float2 yv = *(const float2*)(Y + off);
    float d = degf[node];
    float y0 = yv.x - HSTEP * (d * xv.x - ax);
    float y1 = yv.y - HSTEP * (d * xv.y - ay);
    *(float2*)(Y + off) = make_float2(y0, y1);
    float xn0 = xv.x + HSTEP * y0;
    float xn1 = xv.y + HSTEP * y1;
    *(float2*)(Xn + off) = make_float2(xn0, xn1);
    ushort2 ub; ub.x = f2bf(xn0); ub.y = f2bf(xn1);
    *(ushort2*)(XbfN + off) = ub;
}

// ---------------------------------------------------------------------------
extern "C" void kernel_launch(void* const* d_in, const int* in_sizes, int n_in,
                              void* d_out, int out_size, void* d_ws, size_t ws_size,
                              hipStream_t stream)
{
    const void* x  = d_in[0];
    const int*  ei = (const int*)d_in[1];

    const size_t SZ_NH  = (size_t)N_NODES * HID * sizeof(float);   // 10,240,000
    const size_t SZ_NHB = (size_t)N_NODES * HID * sizeof(u16);     //  5,120,000
    const size_t SZ_I   = 80128;

    char* p = (char*)d_ws;
    float* Xa    = (float*)p; p += SZ_NH;
    float* Xb    = (float*)p; p += SZ_NH;
    float* Y     = (float*)p; p += SZ_NH;
    float* cf    = (float*)p; p += SZ_NH;
    u16*   hbf   = (u16*)p;   p += SZ_NHB;
    u16*   XbfA  = (u16*)p;   p += SZ_NHB;
    u16*   XbfB  = (u16*)p;   p += SZ_NHB;
    int*   deg   = (int*)p;   p += SZ_I;
    int*   fill  = (int*)p;   p += SZ_I;
    int*   rowp  = (int*)p;   p += SZ_I;
    float* degf  = (float*)p; p += SZ_I;
    int*   csr   = (int*)p;   p += (size_t)N_EDGES * sizeof(int);
    int*   flag  = (int*)p;   p += 128;
    float* wsf   = (float*)p; p += 272832 * sizeof(float);
    u16*   WswzF = (u16*)p;   p += 131072 * sizeof(u16);
    u16*   WswzB = (u16*)p;   p += 65536 * sizeof(u16);

    // converted f32 weight sub-pointers (offsets match cvt_off)
    float* Wenc1 = wsf + 0;
    float* benc1 = wsf + 16384;
    float* Wenc2 = wsf + 16512;
    float* benc2 = wsf + 32896;
    float* bihf  = wsf + 164096;
    float* bhhf  = wsf + 164608;
    float* bihb  = wsf + 230656;
    float* bhhb  = wsf + 231168;
    float* Wf1   = wsf + 231680;
    float* bf1   = wsf + 264448;
    float* Wf2   = wsf + 264576;
    float* bf2_  = wsf + 272768;

    float* H1   = Xb;        // encoder intermediate; Xb dead until wave t=1
    u16*   hbbf = (u16*)Y;   // backward h bf16; Y dead after last wave step

    hipMemsetAsync(Y, 0, 2 * SZ_NH + SZ_NHB, stream);   // Y, cf, hbf (contiguous)
    hipMemsetAsync(deg, 0, 2 * SZ_I, stream);           // deg, fill (contiguous)

    // dtype detect + weight conversion (f32 master, swizzled bf16 MFMA copies)
    detect_kernel<<<1, 256, 0, stream>>>((const u16*)x, flag);
    CvtArgs ca;
    ca.s[0] = d_in[2];  ca.s[1] = d_in[3];  ca.s[2] = d_in[4];  ca.s[3] = d_in[5];
    ca.s[4] = d_in[6];  ca.s[5] = d_in[7];  ca.s[6] = d_in[8];  ca.s[7] = d_in[9];
    ca.s[8] = d_in[10]; ca.s[9] = d_in[12]; ca.s[10] = d_in[13];
    ca.s[11] = d_in[14]; ca.s[12] = d_in[15]; ca.s[13] = d_in[16]; ca.s[14] = d_in[17];
    convert_kernel<<<(272832 + 255) / 256, 256, 0, stream>>>(ca, wsf, flag);
    build_wswz_kernel<<<512, 256, 0, stream>>>(wsf, WswzF, WswzB);

    // CSR build
    count_kernel<<<(N_EDGES + 255) / 256, 256, 0, stream>>>(ei, deg);
    scan_kernel<<<1, 1024, 0, stream>>>(deg, rowp, degf);
    fill_kernel<<<(N_EDGES + 255) / 256, 256, 0, stream>>>(ei, rowp, fill, csr);

    const int MB = (N_NODES + 63) / 64;   // 313

    // encoder: H1 = relu(x @ Wenc1^T + b1); Xa = H1 @ Wenc2^T + b2 (+ bf16 copy)
    gemm_kernel<false, false, true, false, false><<<dim3(MB, 2), 256, 0, stream>>>(
        x, nullptr, Wenc1, benc1, H1, nullptr, N_NODES, HID, HID, HID, flag, nullptr);
    gemm_kernel<false, false, false, false, true><<<dim3(MB, 2), 256, 0, stream>>>(
        H1, nullptr, Wenc2, benc2, Xa, XbfA, N_NODES, HID, HID, HID, nullptr, nullptr);

    // wave scan interleaved with forward LSTM (MFMA fused gate-GEMM + cell)
    float* Xbuf[2] = {Xa, Xb};
    u16* XbP = XbfA;   // current Xbf (gather source / LSTM input)
    u16* XbN = XbfB;   // next Xbf (wave output)
    int cur = 0;
    for (int t = 0; t < NSTEPS; ++t) {
        if (t > 0) {
            wave_kernel<<<(N_NODES + 3) / 4, 256, 0, stream>>>(
                Xbuf[cur], Xbuf[1 - cur], XbP, XbN, Y, degf, rowp, csr);
            cur ^= 1;
            u16* tmp = XbP; XbP = XbN; XbN = tmp;
        }
        lstm_mfma_kernel<true><<<N_NODES / 32, 512, 0, stream>>>(
            XbP, hbf, hbf, cf, WswzF, bihf, bhhf);
    }

    // backward LSTM: only hs_b[0] used -> one cell on X_tilde[15], zero state
    lstm_mfma_kernel<false><<<N_NODES / 32, 512, 0, stream>>>(
        XbP, nullptr, hbbf, nullptr, WswzB, bihb, bhhb);

    // head: F1 = relu([hbf | hbbf] @ Wf1^T + bf1); out = F1 @ Wf2^T + bf2
    float* F1 = Xbuf[1 - cur];   // dead X buffer
    gemm_kernel<true, true, true, false, false><<<dim3(MB, 2), 256, 0, stream>>>(
        hbf, hbbf, Wf1, bf1, F1, nullptr, N_NODES, HID, 2 * HID, HID, nullptr, nullptr);
    gemm_kernel<false, false, false, true, false><<<dim3(MB, 1), 256, 0, stream>>>(
        F1, nullptr, Wf2, bf2_, d_out, nullptr, N_NODES, OUT_DIM, HID, HID, nullptr, flag);
}